// Round 2
// baseline (1363.427 us; speedup 1.0000x reference)
//
#include <hip/hip_runtime.h>
#include <hip/hip_bf16.h>
#include <cstdint>

// Sparse top-2 MoE (DBRX experts), MI355X gfx950.
// router -> scan -> assign -> pass1 (silu(X w1^T) -> H1)
//                          -> pass2 (H1 *= X v1^T, in place)
//                          -> pass3 (outslot = gate * (H w2^T)) -> combine.
// Each GEMM pass: 128x128x64 tiles, 4 waves, mfma_16x16x32_bf16, fp32 accum.
// A: bf16, global_load_lds dwordx4, pre-swizzled source + linear LDS dest, double-buffered.
// B: fp32, reg-prefetched one K-step ahead, cvt->bf16, XOR-swizzled ds_write, double-buffered.
// One __syncthreads per K-step (buffer parity makes the second barrier unnecessary).

#define T_TOK 4096
#define DHID  2048
#define NEXP  8
#define IDIM  4096
#define NSLOT (T_TOK * 2)

#define BM 128
#define BN 128
#define BK 64

typedef __bf16 bf16x8 __attribute__((ext_vector_type(8)));
typedef __bf16 bf16x4 __attribute__((ext_vector_type(4)));
typedef float  f32x4  __attribute__((ext_vector_type(4)));

__device__ __forceinline__ void gload_lds16(const void* g, void* l) {
    __builtin_amdgcn_global_load_lds(
        (const __attribute__((address_space(1))) uint32_t*)g,
        (__attribute__((address_space(3))) uint32_t*)l, 16, 0, 0);
}

// ---------------- router: logits, top-2 gates, x -> bf16 ----------------
__global__ __launch_bounds__(256) void router_kernel(
    const float* __restrict__ x, const float* __restrict__ wr,
    __bf16* __restrict__ xb, int* __restrict__ topi, float* __restrict__ topg,
    int* __restrict__ cnt)
{
    int wave = threadIdx.x >> 6, lane = threadIdx.x & 63;
    int t = blockIdx.x * 4 + wave;
    const float4* xr = (const float4*)(x + (size_t)t * DHID);
    bf16x4* xbo = (bf16x4*)(xb + (size_t)t * DHID);
    float acc[NEXP];
#pragma unroll
    for (int e = 0; e < NEXP; ++e) acc[e] = 0.f;
#pragma unroll
    for (int j = 0; j < DHID / 256; ++j) {      // 8 iters of float4
        int d4 = lane + j * 64;
        float4 v = xr[d4];
        bf16x4 bv;
        bv[0] = (__bf16)v.x; bv[1] = (__bf16)v.y;
        bv[2] = (__bf16)v.z; bv[3] = (__bf16)v.w;
        xbo[d4] = bv;
#pragma unroll
        for (int e = 0; e < NEXP; ++e) {
            float4 w = ((const float4*)(wr + e * DHID))[d4];
            acc[e] += v.x * w.x + v.y * w.y + v.z * w.z + v.w * w.w;
        }
    }
#pragma unroll
    for (int e = 0; e < NEXP; ++e) {
#pragma unroll
        for (int s = 32; s > 0; s >>= 1) acc[e] += __shfl_xor(acc[e], s);
    }
    if (lane == 0) {
        int e0 = 0; float l0 = acc[0];
#pragma unroll
        for (int e = 1; e < NEXP; ++e) if (acc[e] > l0) { l0 = acc[e]; e0 = e; }
        int e1 = -1; float l1 = -3.4e38f;
#pragma unroll
        for (int e = 0; e < NEXP; ++e) if (e != e0 && acc[e] > l1) { l1 = acc[e]; e1 = e; }
        float g0 = 1.f / (1.f + __expf(l1 - l0));
        topi[t * 2] = e0; topi[t * 2 + 1] = e1;
        topg[t * 2] = g0; topg[t * 2 + 1] = 1.f - g0;
        atomicAdd(&cnt[e0], 1); atomicAdd(&cnt[e1], 1);
    }
}

__global__ void scan_kernel(const int* __restrict__ cnt, int* __restrict__ basep,
                            int* __restrict__ fill)
{
    if (threadIdx.x == 0 && blockIdx.x == 0) {
        int s = 0;
#pragma unroll
        for (int e = 0; e < NEXP; ++e) { basep[e] = s; s += cnt[e]; fill[e] = 0; }
    }
}

__global__ __launch_bounds__(256) void assign_kernel(
    const int* __restrict__ topi, const float* __restrict__ topg,
    const int* __restrict__ basep, int* __restrict__ fill,
    int* __restrict__ tok_of_slot, float* __restrict__ gate_of_slot,
    int* __restrict__ slot_of)
{
    int t = blockIdx.x * 256 + threadIdx.x;
    if (t >= T_TOK) return;
#pragma unroll
    for (int k = 0; k < 2; ++k) {
        int e = topi[t * 2 + k];
        int slot = basep[e] + atomicAdd(&fill[e], 1);
        tok_of_slot[slot] = t;
        gate_of_slot[slot] = topg[t * 2 + k];
        slot_of[t * 2 + k] = slot;
    }
}

// ---------------- unified GEMM pass ----------------
// PASS 1: Out = silu(A W^T)          A=xb (gather), W=w1, Out=H1
// PASS 2: Out = H1r * (A W^T)        A=xb (gather), W=v1, Out=H1 (in place)
// PASS 3: Out = gate * (A W^T)       A=H (contig),  W=w2, Out=outslot
template <int PASS, int KDIM, int NDIM>
__global__ __launch_bounds__(256, 2) void moe_gemm(
    const __bf16* __restrict__ Abase, const float* __restrict__ W,
    const int* __restrict__ tok_of_slot, const float* __restrict__ gate_of_slot,
    const int* __restrict__ cnt, const int* __restrict__ basep,
    __bf16* Out, const __bf16* H1r)
{
    int e  = blockIdx.z;
    int ne = cnt[e];
    int m0 = blockIdx.y * BM;
    if (m0 >= ne) return;
    int n0 = blockIdx.x * BN;
    int sbase = basep[e] + m0;

    __shared__ __bf16 As[2][BM * BK];
    __shared__ __bf16 Bs[2][BN * BK];
    __shared__ int   toks[BM];
    __shared__ float gates[BM];

    int tid = threadIdx.x;
    if (PASS < 3) {
        if (tid < BM) toks[tid] = (m0 + tid < ne) ? tok_of_slot[sbase + tid] : 0;
    } else {
        if (tid < BM) gates[tid] = gate_of_slot[(m0 + tid < ne) ? (sbase + tid) : sbase];
    }
    __syncthreads();

    const float* We = W + (size_t)e * NDIM * KDIM;
    int lane = tid & 63, wave = tid >> 6;
    int wr0 = (wave >> 1) * 64, wc0 = (wave & 1) * 64;

    char* AsB = (char*)&As[0][0];
    char* BsB = (char*)&Bs[0][0];

    // A staging: 16 chunks of 1 KiB; chunk = wave*4+j (wave-uniform dest).
    // Linear dest; source pre-swizzled so swizzled reads see logical layout.
    const __bf16* a_src[4];
    char* a_dst[4];
    {
        int p = lane & 7;
#pragma unroll
        for (int j = 0; j < 4; ++j) {
            int chunk = wave * 4 + j;
            int arow  = chunk * 8 + (lane >> 3);
            int csw   = p ^ (arow & 7);
            size_t grow;
            if (PASS < 3) {
                grow = (size_t)toks[arow] * DHID;
            } else {
                int srow = (m0 + arow < ne) ? (sbase + arow) : sbase;
                grow = (size_t)srow * KDIM;
            }
            a_src[j] = Abase + grow + csw * 8;
            a_dst[j] = AsB + chunk * 1024;
        }
    }
    // B staging: 4 rows x 8 fp32 per thread, cvt -> bf16x8, XOR-swizzled write.
    int row0 = tid >> 3, ch = tid & 7;
    const float* b_src[4];
    int dstoff[4];
#pragma unroll
    for (int p = 0; p < 4; ++p) {
        int row = row0 + 32 * p;
        b_src[p] = We + (size_t)(n0 + row) * KDIM + ch * 8;
        dstoff[p] = row * 128 + ((ch * 16) ^ ((row & 7) << 4));
    }

    f32x4 acc[4][4];
    f32x4 zf = {0.f, 0.f, 0.f, 0.f};
#pragma unroll
    for (int m = 0; m < 4; ++m)
#pragma unroll
        for (int n = 0; n < 4; ++n) acc[m][n] = zf;

    float4 pb[8];

    // prologue: issue A(0) gload_lds, load B(0) into regs
#pragma unroll
    for (int j = 0; j < 4; ++j) gload_lds16(a_src[j], a_dst[j]);
#pragma unroll
    for (int p = 0; p < 4; ++p) {
        pb[2 * p]     = *(const float4*)(b_src[p]);
        pb[2 * p + 1] = *(const float4*)(b_src[p] + 4);
    }

    const int NK = KDIM / BK;
    for (int kt = 0; kt < NK; ++kt) {
        int cur = kt & 1;
        // cvt + swizzled write B(kt)
#pragma unroll
        for (int p = 0; p < 4; ++p) {
            float4 fa = pb[2 * p], fb = pb[2 * p + 1];
            bf16x8 bv;
            bv[0]=(__bf16)fa.x; bv[1]=(__bf16)fa.y; bv[2]=(__bf16)fa.z; bv[3]=(__bf16)fa.w;
            bv[4]=(__bf16)fb.x; bv[5]=(__bf16)fb.y; bv[6]=(__bf16)fb.z; bv[7]=(__bf16)fb.w;
            *(bf16x8*)(BsB + cur * 16384 + dstoff[p]) = bv;
        }
        __syncthreads();   // drains vmcnt: A(kt) landed; B(kt) writes visible
        if (kt + 1 < NK) {
            int nxt = cur ^ 1;
            int koff = (kt + 1) * BK;
#pragma unroll
            for (int j = 0; j < 4; ++j)
                gload_lds16(a_src[j] + koff, a_dst[j] + nxt * 16384);
#pragma unroll
            for (int p = 0; p < 4; ++p) {
                pb[2 * p]     = *(const float4*)(b_src[p] + koff);
                pb[2 * p + 1] = *(const float4*)(b_src[p] + koff + 4);
            }
        }
        // compute tile kt
#pragma unroll
        for (int ks = 0; ks < 2; ++ks) {
            bf16x8 af[4], bfr[4];
#pragma unroll
            for (int m = 0; m < 4; ++m) {
                int row = wr0 + m * 16 + (lane & 15);
                af[m] = *(const bf16x8*)(AsB + cur * 16384 + row * 128 +
                                         ((ks * 64 + (lane >> 4) * 16) ^ ((row & 7) << 4)));
            }
#pragma unroll
            for (int n = 0; n < 4; ++n) {
                int row = wc0 + n * 16 + (lane & 15);
                bfr[n] = *(const bf16x8*)(BsB + cur * 16384 + row * 128 +
                                          ((ks * 64 + (lane >> 4) * 16) ^ ((row & 7) << 4)));
            }
#pragma unroll
            for (int m = 0; m < 4; ++m)
#pragma unroll
                for (int n = 0; n < 4; ++n)
                    acc[m][n] = __builtin_amdgcn_mfma_f32_16x16x32_bf16(af[m], bfr[n], acc[m][n], 0, 0, 0);
        }
    }

    // epilogue
#pragma unroll
    for (int m = 0; m < 4; ++m) {
        int rbase = wr0 + m * 16 + ((lane >> 4) * 4);
#pragma unroll
        for (int n = 0; n < 4; ++n) {
            int col = n0 + wc0 + n * 16 + (lane & 15);
#pragma unroll
            for (int r = 0; r < 4; ++r) {
                int lrow = rbase + r;
                if (m0 + lrow < ne) {
                    size_t oidx = (size_t)(sbase + lrow) * NDIM + col;
                    float v = acc[m][n][r];
                    if (PASS == 1) {
                        v = v / (1.f + __expf(-v));
                    } else if (PASS == 2) {
                        v = (float)H1r[oidx] * v;
                    } else {
                        v = v * gates[lrow];
                    }
                    Out[oidx] = (__bf16)v;
                }
            }
        }
    }
}

// ---------------- combine: out[t] = outslot[s0] + outslot[s1] ----------------
__global__ __launch_bounds__(256) void combine_kernel(
    const __bf16* __restrict__ outslot, const int* __restrict__ slot_of,
    float* __restrict__ out)
{
    int idx = blockIdx.x * 256 + threadIdx.x;
    int t = idx >> 8;
    int c = (idx & 255) * 8;
    int s0 = slot_of[t * 2], s1 = slot_of[t * 2 + 1];
    bf16x8 a = *(const bf16x8*)(outslot + (size_t)s0 * DHID + c);
    bf16x8 b = *(const bf16x8*)(outslot + (size_t)s1 * DHID + c);
    float4 o0, o1;
    o0.x = (float)a[0] + (float)b[0];
    o0.y = (float)a[1] + (float)b[1];
    o0.z = (float)a[2] + (float)b[2];
    o0.w = (float)a[3] + (float)b[3];
    o1.x = (float)a[4] + (float)b[4];
    o1.y = (float)a[5] + (float)b[5];
    o1.z = (float)a[6] + (float)b[6];
    o1.w = (float)a[7] + (float)b[7];
    *(float4*)(out + (size_t)t * DHID + c)     = o0;
    *(float4*)(out + (size_t)t * DHID + c + 4) = o1;
}

extern "C" void kernel_launch(void* const* d_in, const int* in_sizes, int n_in,
                              void* d_out, int out_size, void* d_ws, size_t ws_size,
                              hipStream_t stream)
{
    (void)in_sizes; (void)n_in; (void)out_size; (void)ws_size;
    const float* x  = (const float*)d_in[0];
    const float* wr = (const float*)d_in[1];
    const float* w1 = (const float*)d_in[2];
    const float* v1 = (const float*)d_in[3];
    const float* w2 = (const float*)d_in[4];
    float* out = (float*)d_out;

    char* ws = (char*)d_ws;
    size_t off = 0;
    auto alloc = [&](size_t bytes) -> void* {
        void* p = ws + off;
        off += bytes;
        off = (off + 255) & ~(size_t)255;
        return p;
    };
    __bf16* xb      = (__bf16*)alloc((size_t)T_TOK * DHID * 2);
    __bf16* H1      = (__bf16*)alloc((size_t)NSLOT * IDIM * 2);   // holds silu(XW1^T), then H in place
    __bf16* outslot = (__bf16*)alloc((size_t)NSLOT * DHID * 2);
    int*    topi    = (int*)  alloc((size_t)T_TOK * 2 * 4);
    float*  topg    = (float*)alloc((size_t)T_TOK * 2 * 4);
    int*    tok_of_slot  = (int*)  alloc((size_t)NSLOT * 4);
    float*  gate_of_slot = (float*)alloc((size_t)NSLOT * 4);
    int*    slot_of = (int*)  alloc((size_t)NSLOT * 4);
    int*    cnt     = (int*)  alloc(NEXP * 4);
    int*    basep   = (int*)  alloc(NEXP * 4);
    int*    fill    = (int*)  alloc(NEXP * 4);

    hipMemsetAsync(cnt, 0, NEXP * 4, stream);
    router_kernel<<<T_TOK / 4, 256, 0, stream>>>(x, wr, xb, topi, topg, cnt);
    scan_kernel<<<1, 64, 0, stream>>>(cnt, basep, fill);
    assign_kernel<<<T_TOK / 256, 256, 0, stream>>>(topi, topg, basep, fill,
                                                   tok_of_slot, gate_of_slot, slot_of);
    moe_gemm<1, DHID, IDIM><<<dim3(IDIM / BN, T_TOK / BM, NEXP), 256, 0, stream>>>(
        xb, w1, tok_of_slot, gate_of_slot, cnt, basep, H1, nullptr);
    moe_gemm<2, DHID, IDIM><<<dim3(IDIM / BN, T_TOK / BM, NEXP), 256, 0, stream>>>(
        xb, v1, tok_of_slot, gate_of_slot, cnt, basep, H1, H1);
    moe_gemm<3, IDIM, DHID><<<dim3(DHID / BN, T_TOK / BM, NEXP), 256, 0, stream>>>(
        H1, w2, tok_of_slot, gate_of_slot, cnt, basep, outslot, nullptr);
    combine_kernel<<<(T_TOK * DHID / 8) / 256, 256, 0, stream>>>(outslot, slot_of, out);
}